// Round 5
// baseline (234.935 us; speedup 1.0000x reference)
//
#include <hip/hip_runtime.h>
#include <math.h>

// ---------------------------------------------------------------------------
// R5: kernel-count collapse (9 -> 5 + memset) and wide build loads.
//  - bin_sort absorbs transform1 (t1=x@Wr1, z1=x@Wo1+b1) as phase 0 and
//    accumulates per-bucket totals via global atomics (replaces transpose+btot).
//  - per-(block,bucket) runs in `packed` are padded to 4-aligned so
//    bucket_sort gathers them with uint4 loads (tail masked in regs).
//  - bucket_sort computes its own bucket region start from btot (replaces
//    bscan) and emits 4-aligned padded csr rows.
//  - layers: agg1 (no matmul), gcn2_fused (+layer-3 transform), agg3_mlp.
// ---------------------------------------------------------------------------

#define CHUNK  8192        // edges per bin_sort block
#define PSTR   10752       // padded region stride: CHUNK + 4-align pad slack
#define BW     128         // nodes per bucket (dst >> 7)
#define MAXB   6144        // max padded edges per bucket
#define MAXNB  800         // >= NB = 782
#define MAXBLK 512         // >= NBLK = 391

typedef _Float16 half8 __attribute__((ext_vector_type(8)));

static __device__ __forceinline__ float sigmoidf_(float x) {
    return 1.0f / (1.0f + expf(-x));
}

// exclusive 256-scan; s[255] holds the inclusive total afterwards
static __device__ __forceinline__ int scan256_excl(int v, int* s) {
    int tid = threadIdx.x;
    s[tid] = v;
    for (int off = 1; off < 256; off <<= 1) {
        __syncthreads();
        int t = (tid >= off) ? s[tid - off] : 0;
        __syncthreads();
        s[tid] += t;
    }
    __syncthreads();
    return s[tid] - v;
}

// mean of t[src] over one node's csr row (rs 4-aligned; int4 index loads)
static __device__ __forceinline__ void gather_mean8(
    const half8* __restrict__ t, const int* __restrict__ csr,
    int rs, int d, float* s) {
#pragma unroll
    for (int c = 0; c < 8; ++c) s[c] = 0.0f;
    int e = 0;
    for (; e + 4 <= d; e += 4) {
        int4 ci = *(const int4*)(csr + rs + e);
        half8 v0 = t[ci.x]; half8 v1 = t[ci.y];
        half8 v2 = t[ci.z]; half8 v3 = t[ci.w];
#pragma unroll
        for (int c = 0; c < 8; ++c)
            s[c] += ((float)v0[c] + (float)v1[c]) + ((float)v2[c] + (float)v3[c]);
    }
    for (; e < d; ++e) {
        half8 v = t[csr[rs + e]];
#pragma unroll
        for (int c = 0; c < 8; ++c) s[c] += (float)v[c];
    }
    float inv = 1.0f / (float)(d > 0 ? d : 1);
#pragma unroll
    for (int c = 0; c < 8; ++c) s[c] *= inv;
}

// ---- bin_sort + transform1 + btot accumulation ---------------------------
__global__ __launch_bounds__(256)
void bin_sort_kernel(const float* __restrict__ x, const float* __restrict__ W1r,
                     const float* __restrict__ b1v, const float* __restrict__ W1o,
                     _Float16* __restrict__ t1, _Float16* __restrict__ z1,
                     const int* __restrict__ src, const int* __restrict__ dst,
                     unsigned* __restrict__ packed, int* __restrict__ counts_bm,
                     int* __restrict__ lstart_bm, int* __restrict__ btot,
                     int E, int N, int NB, int NBLK) {
    __shared__ int s_hist[MAXNB];
    __shared__ int s_cur[MAXNB];
    __shared__ unsigned s_pk[PSTR];
    __shared__ int s_scan[256];
    __shared__ float sW[264];          // Wr1(128) Wo1(128) b1(8)
    int tid = threadIdx.x, blk = blockIdx.x;

    // phase 0: layer-1 transform (independent of sort; one node per thread)
    if (tid < 128) { sW[tid] = W1r[tid]; sW[128 + tid] = W1o[tid]; }
    if (tid < 8) sW[256 + tid] = b1v[tid];
    for (int i = tid; i < NB; i += 256) s_hist[i] = 0;
    __syncthreads();
    {
        int node = blk * 256 + tid;
        if (node < N) {
            const float4* x4 = (const float4*)x;
            float xv[16];
#pragma unroll
            for (int k = 0; k < 4; ++k) {
                float4 v = x4[node * 4 + k];
                xv[4 * k] = v.x; xv[4 * k + 1] = v.y;
                xv[4 * k + 2] = v.z; xv[4 * k + 3] = v.w;
            }
            float ta[8], za[8];
#pragma unroll
            for (int j = 0; j < 8; ++j) { ta[j] = 0.0f; za[j] = sW[256 + j]; }
#pragma unroll
            for (int f = 0; f < 16; ++f) {
                float xf = xv[f];
#pragma unroll
                for (int j = 0; j < 8; ++j) {
                    ta[j] += xf * sW[f * 8 + j];
                    za[j] += xf * sW[128 + f * 8 + j];
                }
            }
            half8 th, zh;
#pragma unroll
            for (int j = 0; j < 8; ++j) { th[j] = (_Float16)ta[j]; zh[j] = (_Float16)za[j]; }
            ((half8*)t1)[node] = th;
            ((half8*)z1)[node] = zh;
        }
    }

    if (blk >= NBLK) return;   // transform-only blocks (none for default shape)

    int base = blk * CHUNK;
    int cnt = E - base; if (cnt > CHUNK) cnt = CHUNK;

    // phase 1: histogram of dst buckets
    if (cnt == CHUNK) {
        const int4* d4 = (const int4*)(dst + base);
#pragma unroll
        for (int k = 0; k < CHUNK / 1024; ++k) {
            int4 d = d4[k * 256 + tid];
            atomicAdd(&s_hist[d.x >> 7], 1);
            atomicAdd(&s_hist[d.y >> 7], 1);
            atomicAdd(&s_hist[d.z >> 7], 1);
            atomicAdd(&s_hist[d.w >> 7], 1);
        }
    } else {
        for (int i = tid; i < cnt; i += 256) atomicAdd(&s_hist[dst[base + i] >> 7], 1);
    }
    __syncthreads();

    // phase 2: exclusive scan of 4-aligned bucket sizes -> padded starts
    int per = (NB + 255) / 256;
    int st = tid * per;
    int lsum = 0;
    for (int j = 0; j < per; ++j)
        if (st + j < NB) lsum += (s_hist[st + j] + 3) & ~3;
    int excl = scan256_excl(lsum, s_scan);
    int padtot = s_scan[255];
    int run = excl;
    for (int j = 0; j < per; ++j)
        if (st + j < NB) { s_cur[st + j] = run; run += (s_hist[st + j] + 3) & ~3; }
    __syncthreads();

    // phase 3: re-read (L2-hot) and scatter into LDS, bucket-sorted + padded
    if (cnt == CHUNK) {
        const int4* d4 = (const int4*)(dst + base);
        const int4* s4 = (const int4*)(src + base);
#pragma unroll
        for (int k = 0; k < CHUNK / 1024; ++k) {
            int4 d = d4[k * 256 + tid];
            int4 s = s4[k * 256 + tid];
            int dd[4] = {d.x, d.y, d.z, d.w};
            int ss[4] = {s.x, s.y, s.z, s.w};
#pragma unroll
            for (int j = 0; j < 4; ++j) {
                int pos = atomicAdd(&s_cur[dd[j] >> 7], 1);
                s_pk[pos] = ((unsigned)(dd[j] & 127) << 17) | (unsigned)ss[j];
            }
        }
    } else {
        for (int i = tid; i < cnt; i += 256) {
            int d = dst[base + i], s = src[base + i];
            int pos = atomicAdd(&s_cur[d >> 7], 1);
            s_pk[pos] = ((unsigned)(d & 127) << 17) | (unsigned)s;
        }
    }
    __syncthreads();

    // phase 4: block-major write (padded length) + tables + bucket totals
    for (int i = tid; i < padtot; i += 256) packed[(size_t)blk * PSTR + i] = s_pk[i];
    for (int i = tid; i < NB; i += 256) {
        int h = s_hist[i];
        counts_bm[blk * NB + i] = h;
        lstart_bm[blk * NB + i] = s_cur[i] - h;   // cur advanced by exactly h
        if (h) atomicAdd(&btot[i], h);
    }
}

// ---- bucket_sort: self-computed region start, uint4 run gather -----------
__global__ __launch_bounds__(256)
void bucket_sort_kernel(const unsigned* __restrict__ packed,
                        const int* __restrict__ counts_bm,
                        const int* __restrict__ lstart_bm,
                        const int* __restrict__ btot,
                        int* __restrict__ csr_src, int* __restrict__ deg,
                        int* __restrict__ rowstart, int N, int NB, int NBLK) {
    __shared__ int s_cnt[MAXBLK], s_lst[MAXBLK], s_off[MAXBLK];
    __shared__ unsigned s_p[MAXB];
    __shared__ int s_out[MAXB];
    __shared__ int h[BW], hs[BW], curb[BW];
    __shared__ int s_scan[256];
    __shared__ int s_tot, s_ptot;
    int b = blockIdx.x, tid = threadIdx.x;

    // region start: prefix over buckets i<b of (align4(btot[i]) + 512)
    int partial = 0;
    for (int i = tid; i < b; i += 256) partial += ((btot[i] + 3) & ~3) + 512;
    scan256_excl(partial, s_scan);
    int beg = s_scan[255];

    for (int i = tid; i < NBLK; i += 256) {
        s_cnt[i] = counts_bm[i * NB + b];       // strided column read (3KB)
        s_lst[i] = lstart_bm[i * NB + b];
    }
    __syncthreads();

    // exclusive scan of run counts -> staging offsets
    int per = (NBLK + 255) / 256;
    int st = tid * per;
    int lsum = 0;
    for (int j = 0; j < per; ++j)
        if (st + j < NBLK) lsum += s_cnt[st + j];
    int excl = scan256_excl(lsum, s_scan);
    if (tid == 255) s_tot = s_scan[255];
    int run = excl;
    for (int j = 0; j < per; ++j)
        if (st + j < NBLK) { s_off[st + j] = run; run += s_cnt[st + j]; }
    __syncthreads();
    int cnt = s_tot; if (cnt > MAXB) cnt = MAXB;

    // gather this bucket's runs with uint4 loads (runs are 4-aligned)
    for (int blk = tid; blk < NBLK; blk += 256) {
        int c = s_cnt[blk], o = s_off[blk];
        const uint4* p = (const uint4*)(packed + (size_t)blk * PSTR + s_lst[blk]);
        for (int j = 0; j < c; j += 4) {
            uint4 v = p[j >> 2];
            int r = c - j;
            s_p[o + j] = v.x;
            if (r > 1) s_p[o + j + 1] = v.y;
            if (r > 2) s_p[o + j + 2] = v.z;
            if (r > 3) s_p[o + j + 3] = v.w;
        }
    }
    if (tid < BW) h[tid] = 0;
    __syncthreads();

    for (int i = tid; i < cnt; i += 256) atomicAdd(&h[s_p[i] >> 17], 1);
    __syncthreads();
    if (tid == 0) {
        int acc = 0;
        for (int i = 0; i < BW; ++i) { hs[i] = acc; acc += (h[i] + 3) & ~3; }
        s_ptot = acc;
    }
    __syncthreads();
    if (tid < BW) {
        curb[tid] = hs[tid];
        int node = b * BW + tid;
        if (node < N) { deg[node] = h[tid]; rowstart[node] = beg + hs[tid]; }
    }
    __syncthreads();
    for (int i = tid; i < cnt; i += 256) {
        unsigned p = s_p[i];
        int pos = atomicAdd(&curb[p >> 17], 1);
        s_out[pos] = (int)(p & 0x1FFFF);
    }
    __syncthreads();
    int ptot = s_ptot; if (ptot > MAXB) ptot = MAXB;
    for (int i = tid; i < ptot; i += 256) csr_src[beg + i] = s_out[i];
}

// ---- layer 1: h1 = sigmoid(mean(t1) + z1) --------------------------------
__global__ __launch_bounds__(256)
void agg1_kernel(const _Float16* __restrict__ t1, const _Float16* __restrict__ z1,
                 const int* __restrict__ rowstart, const int* __restrict__ deg,
                 const int* __restrict__ csr, _Float16* __restrict__ h1, int n) {
    int node = blockIdx.x * 256 + threadIdx.x;
    if (node >= n) return;
    float s[8];
    gather_mean8((const half8*)t1, csr, rowstart[node], deg[node], s);
    half8 z = ((const half8*)z1)[node];
    half8 o;
#pragma unroll
    for (int c = 0; c < 8; ++c) o[c] = (_Float16)sigmoidf_(s[c] + (float)z[c]);
    ((half8*)h1)[node] = o;
}

// ---- layer 2 + layer-3 transform, all in registers -----------------------
__global__ __launch_bounds__(256)
void gcn2_fused_kernel(const _Float16* __restrict__ h1,
                       const int* __restrict__ rowstart, const int* __restrict__ deg,
                       const int* __restrict__ csr,
                       const float* __restrict__ W2r, const float* __restrict__ b2,
                       const float* __restrict__ W2o,
                       const float* __restrict__ W3r, const float* __restrict__ b3,
                       const float* __restrict__ W3o,
                       _Float16* __restrict__ t3, _Float16* __restrict__ z3, int n) {
    __shared__ float sW2r[128], sW2o[128], sW3r[128], sW3o[128], sb2[16], sb3[8];
    int tid = threadIdx.x;
    if (tid < 128) {
        sW2r[tid] = W2r[tid]; sW2o[tid] = W2o[tid];
        sW3r[tid] = W3r[tid]; sW3o[tid] = W3o[tid];
    }
    if (tid < 16) sb2[tid] = b2[tid];
    if (tid < 8) sb3[tid] = b3[tid];
    __syncthreads();
    int node = blockIdx.x * 256 + tid;
    if (node >= n) return;

    float m[8];
    gather_mean8((const half8*)h1, csr, rowstart[node], deg[node], m);
    half8 sf = ((const half8*)h1)[node];
    float x8[8];
#pragma unroll
    for (int c = 0; c < 8; ++c) x8[c] = (float)sf[c];

    float v16[16];
#pragma unroll
    for (int j = 0; j < 16; ++j) {
        float a = sb2[j];
#pragma unroll
        for (int f = 0; f < 8; ++f)
            a += m[f] * sW2r[f * 16 + j] + x8[f] * sW2o[f * 16 + j];
        v16[j] = sigmoidf_(a);
    }
    float ta[8], za[8];
#pragma unroll
    for (int j = 0; j < 8; ++j) { ta[j] = 0.0f; za[j] = sb3[j]; }
#pragma unroll
    for (int f = 0; f < 16; ++f) {
        float hv = v16[f];
#pragma unroll
        for (int j = 0; j < 8; ++j) {
            ta[j] += hv * sW3r[f * 8 + j];
            za[j] += hv * sW3o[f * 8 + j];
        }
    }
    half8 th, zh;
#pragma unroll
    for (int j = 0; j < 8; ++j) { th[j] = (_Float16)ta[j]; zh[j] = (_Float16)za[j]; }
    ((half8*)t3)[node] = th;
    ((half8*)z3)[node] = zh;
}

// ---- layer 3 + full MLP head ---------------------------------------------
__global__ __launch_bounds__(256)
void agg3_mlp_kernel(const _Float16* __restrict__ t3, const _Float16* __restrict__ z3,
                     const int* __restrict__ rowstart, const int* __restrict__ deg,
                     const int* __restrict__ csr,
                     const float* __restrict__ fc1W, const float* __restrict__ fc1b,
                     const float* __restrict__ fc2W, const float* __restrict__ fc2b,
                     float* __restrict__ out, int n) {
    __shared__ float sW1[256], sb1[32], sW2[32];
    __shared__ float sb2_;
    int tid = threadIdx.x;
    if (tid < 256) sW1[tid] = fc1W[tid];
    if (tid < 32) { sb1[tid] = fc1b[tid]; sW2[tid] = fc2W[tid]; }
    if (tid == 0) sb2_ = fc2b[0];
    __syncthreads();
    int node = blockIdx.x * 256 + tid;
    if (node >= n) return;

    float s[8];
    gather_mean8((const half8*)t3, csr, rowstart[node], deg[node], s);
    half8 z = ((const half8*)z3)[node];
    float h[8];
#pragma unroll
    for (int c = 0; c < 8; ++c) h[c] = sigmoidf_(s[c] + (float)z[c]);

    float acc = sb2_;
#pragma unroll
    for (int j = 0; j < 32; ++j) {
        float a = sb1[j];
#pragma unroll
        for (int f = 0; f < 8; ++f) a += h[f] * sW1[f * 32 + j];
        acc += sW2[j] * sigmoidf_(a);
    }
    out[node] = acc;
}

extern "C" void kernel_launch(void* const* d_in, const int* in_sizes, int n_in,
                              void* d_out, int out_size, void* d_ws, size_t ws_size,
                              hipStream_t stream) {
    const float* x      = (const float*)d_in[0];
    const int*   ei     = (const int*)d_in[1];
    const float* Wrel1  = (const float*)d_in[2];
    const float* b1     = (const float*)d_in[3];
    const float* Wroot1 = (const float*)d_in[4];
    const float* Wrel2  = (const float*)d_in[5];
    const float* b2     = (const float*)d_in[6];
    const float* Wroot2 = (const float*)d_in[7];
    const float* Wrel3  = (const float*)d_in[8];
    const float* b3     = (const float*)d_in[9];
    const float* Wroot3 = (const float*)d_in[10];
    const float* fc1W   = (const float*)d_in[11];
    const float* fc1b   = (const float*)d_in[12];
    const float* fc2W   = (const float*)d_in[13];
    const float* fc2b   = (const float*)d_in[14];
    float* out = (float*)d_out;

    const int N = in_sizes[0] / 16;
    const int E = in_sizes[1] / 2;
    const int* e_src = ei;
    const int* e_dst = ei + E;

    const int NB   = (N + BW - 1) / BW;           // 782
    const int NBLK = (E + CHUNK - 1) / CHUNK;     // 391
    const int nbN  = (N + 255) / 256;             // 391

    char* ws = (char*)d_ws;
    size_t off = 0;
    auto alloc = [&](size_t bytes) { char* p = ws + off; off += (bytes + 15) & ~size_t(15); return p; };
    unsigned* packed   = (unsigned*)alloc((size_t)NBLK * PSTR * 4);
    int* counts_bm     = (int*)alloc((size_t)NBLK * NB * 4);
    int* lstart_bm     = (int*)alloc((size_t)NBLK * NB * 4);
    int* btot          = (int*)alloc((size_t)NB * 4);
    int* csr_src       = (int*)alloc(((size_t)E + (size_t)NB * 516) * 4);
    int* deg           = (int*)alloc((size_t)N * 4);
    int* rowstart      = (int*)alloc((size_t)N * 4);
    _Float16* t1       = (_Float16*)alloc((size_t)N * 8 * 2);
    _Float16* z1       = (_Float16*)alloc((size_t)N * 8 * 2);
    _Float16* h1       = (_Float16*)alloc((size_t)N * 8 * 2);
    _Float16* t3       = (_Float16*)alloc((size_t)N * 8 * 2);
    _Float16* z3       = (_Float16*)alloc((size_t)N * 8 * 2);

    hipMemsetAsync(btot, 0, (size_t)NB * 4, stream);

    const int gbuild = (NBLK > nbN) ? NBLK : nbN;
    bin_sort_kernel<<<gbuild, 256, 0, stream>>>(
        x, Wrel1, b1, Wroot1, t1, z1, e_src, e_dst,
        packed, counts_bm, lstart_bm, btot, E, N, NB, NBLK);
    bucket_sort_kernel<<<NB, 256, 0, stream>>>(packed, counts_bm, lstart_bm, btot,
                                               csr_src, deg, rowstart, N, NB, NBLK);
    agg1_kernel<<<nbN, 256, 0, stream>>>(t1, z1, rowstart, deg, csr_src, h1, N);
    gcn2_fused_kernel<<<nbN, 256, 0, stream>>>(h1, rowstart, deg, csr_src,
                                               Wrel2, b2, Wroot2, Wrel3, b3, Wroot3, t3, z3, N);
    agg3_mlp_kernel<<<nbN, 256, 0, stream>>>(t3, z3, rowstart, deg, csr_src,
                                             fc1W, fc1b, fc2W, fc2b, out, N);
}